// Round 10
// baseline (185.262 us; speedup 1.0000x reference)
//
#include <hip/hip_runtime.h>
#include <hip/hip_bf16.h>

// Problem constants (B=1)
#define T_SEQ   1024
#define C_MODEL 768
#define N_BR    12
#define DH      64
#define H_TOT   144          // N_BR * N_BR
#define NQ      9216         // C_MODEL * N_BR

typedef __bf16 bf16x8 __attribute__((ext_vector_type(8)));
typedef float  f32x4  __attribute__((ext_vector_type(4)));
typedef unsigned int u32x4 __attribute__((ext_vector_type(4)));
typedef unsigned short u16;

// fixed softmax offset (scores ~N(0,0.3); exact softmax for any offset)
#define SM_OFF 3.0f
#define LOG2E  1.44269504089f
#define QSCALE (0.125f * LOG2E)     // folded into Q: scores come out in log2 units

// ---------------------------------------------------------------------------
// helpers
// ---------------------------------------------------------------------------
__device__ __forceinline__ void gload16(void* lds, const void* g)
{
    __builtin_amdgcn_global_load_lds(
        (const __attribute__((address_space(1))) void*)g,
        (__attribute__((address_space(3))) void*)lds, 16, 0, 0);
}

__device__ __forceinline__ void split1(float x, u16& h, u16& l)
{
    __bf16 bh = (__bf16)x;
    __bf16 bl = (__bf16)(x - (float)bh);
    h = __builtin_bit_cast(u16, bh);
    l = __builtin_bit_cast(u16, bl);
}

__device__ __forceinline__ u16 tobf(float x)
{
    return __builtin_bit_cast(u16, (__bf16)x);
}

// packed f32x2 -> bf16x2 (low = a, high = b)
__device__ __forceinline__ unsigned cvtpk(float a, float b)
{
    unsigned r;
    asm("v_cvt_pk_bf16_f32 %0, %1, %2" : "=v"(r) : "v"(a), "v"(b));
    return r;
}

// raw v_exp_f32: 2^x
__device__ __forceinline__ float exp2raw(float x)
{
    float r;
    asm("v_exp_f32 %0, %1" : "=v"(r) : "v"(x));
    return r;
}

// counted-vmcnt barrier: wait own wave's oldest loads, then block barrier.
#define PIPE_WAIT(N_STR)                                        \
    asm volatile("s_waitcnt vmcnt(" N_STR ")" ::: "memory");    \
    __builtin_amdgcn_s_barrier();                               \
    __builtin_amdgcn_sched_barrier(0);

// bijective XCD swizzle (requires nwg % 8 == 0)
__device__ __forceinline__ int xcd_swz(int bid, int nwg)
{
    return (bid & 7) * (nwg >> 3) + (bid >> 3);
}

// swizzled LDS byte address for 128B-row tiles
__device__ __forceinline__ int swb(int row, int byteoff)
{
    return row * 128 + (byteoff ^ ((row & 7) << 4));
}

__device__ __forceinline__ bf16x8 ldsr8(const u16* p, int byteoff)
{
    return *reinterpret_cast<const bf16x8*>(reinterpret_cast<const char*>(p) + byteoff);
}

// ---------------------------------------------------------------------------
// mega prep kernel: rope table + M build + mean bias + x->bf16 + W transposes
// ---------------------------------------------------------------------------
__device__ __forceinline__ void convt_body(const float* __restrict__ W,
                                           u16* __restrict__ out, int K, int N,
                                           int nx, int ky, float (*t)[33], int tid)
{
    const int n0 = nx * 32;
    const int k0 = ky * 32;
    const int tx = tid & 31;
    const int ty = tid >> 5;
    #pragma unroll
    for (int r = 0; r < 4; ++r)
        t[ty + r * 8][tx] = W[(size_t)(k0 + ty + r * 8) * N + n0 + tx];
    __syncthreads();
    #pragma unroll
    for (int r = 0; r < 4; ++r)
        out[(size_t)(n0 + ty + r * 8) * K + k0 + tx] = tobf(t[tx][ty + r * 8]);
}

__global__ __launch_bounds__(256)
void prep_kernel(const float* __restrict__ x, u16* __restrict__ xh,
                 const float* __restrict__ Amat, const float* __restrict__ id_bias,
                 u16* __restrict__ Mth, u16* __restrict__ Mtl,
                 const float* __restrict__ WO_b, float* __restrict__ mbias,
                 float* __restrict__ tab,
                 const float* __restrict__ WO_w, u16* __restrict__ wot,
                 const float* __restrict__ WK_w, const float* __restrict__ WV_w,
                 u16* __restrict__ wkvt)
{
    __shared__ float tsh[32][33];
    const int b   = blockIdx.x;
    const int tid = threadIdx.x;

    if (b < 128) {                       // rope cos/sin table
        const int idx = b * 256 + tid;
        const int t = idx >> 5, i = idx & 31;
        const float inv = expf(-(float)i * (logf(10000.f) / 32.f));
        const float fr = (float)t * inv;
        tab[t * 64 + i]      = cosf(fr);
        tab[t * 64 + 32 + i] = sinf(fr);
    } else if (b < 272) {                // per-head M^T (hi/lo)
        const int h = b - 128;
        const int base = tid * 16;
        #pragma unroll
        for (int i = 0; i < 16; ++i) {
            const int idx = base + i;
            const int e = idx >> 6, d = idx & 63;
            float v = Amat[d * 64 + e] - Amat[e * 64 + d];
            if (d == e) v += 1.0f + id_bias[h * 64 + d];
            u16 hh, ll;
            split1(v, hh, ll);
            Mth[(size_t)h * 4096 + idx] = hh;
            Mtl[(size_t)h * 4096 + idx] = ll;
        }
    } else if (b < 275) {                // mean of WO_b
        const int d = (b - 272) * 256 + tid;
        if (d < C_MODEL) {
            float s = 0.f;
            #pragma unroll
            for (int n = 0; n < N_BR; ++n) s += WO_b[n * C_MODEL + d];
            mbias[d] = s * (1.0f / 12.0f);
        }
    } else if (b < 1043) {               // x -> bf16
        const size_t i = (size_t)(b - 275) * 1024 + tid * 4;
        float4 v = *reinterpret_cast<const float4*>(&x[i]);
        ushort4 o = { tobf(v.x), tobf(v.y), tobf(v.z), tobf(v.w) };
        *reinterpret_cast<ushort4*>(&xh[i]) = o;
    } else if (b < 7955) {               // WO^T bf16 [768][9216]
        const int u = b - 1043;
        convt_body(WO_w, wot, NQ, C_MODEL, u % 24, u / 24, tsh, tid);
    } else if (b < 8531) {               // WK^T bf16 [768][768]
        const int u = b - 7955;
        convt_body(WK_w, wkvt, C_MODEL, C_MODEL, u % 24, u / 24, tsh, tid);
    } else {                             // WV^T bf16 [768][768]
        const int u = b - 8531;
        convt_body(WV_w, wkvt + 589824, C_MODEL, C_MODEL, u % 24, u / 24, tsh, tid);
    }
}

// ---------------------------------------------------------------------------
// plain-bf16 MFMA GEMM (NT), 128x128 tile, BK=32, split-K, XCD-swizzled,
// 3-buffer counted-vmcnt pipeline. (K/V projection)
// ---------------------------------------------------------------------------
#define BM 128
#define BN 128
#define BK 32

__global__ __launch_bounds__(256)
void gemm_bf16_kernel(const u16* __restrict__ A, const u16* __restrict__ B,
                      float* __restrict__ Cp, int M, int N, int K,
                      int nx, int ny, int nz)
{
    __shared__ __align__(16) u16 sA[3][BM * BK], sB[3][BN * BK];   // 48KB

    const int nwg = nx * ny * nz;
    const int wg  = xcd_swz(blockIdx.x, nwg);
    const int x   = wg % nx;
    const int y   = (wg / nx) % ny;
    const int z   = wg / (nx * ny);

    const int tid  = threadIdx.x;
    const int lane = tid & 63;
    const int wid  = tid >> 6;
    const int m0   = y * BM;
    const int n0   = x * BN;
    const int kc   = K / nz;
    const int kbeg = z * kc;
    const int kend = kbeg + kc;

    const int wm = (wid >> 1) * 64;
    const int wn = (wid & 1) * 64;

    f32x4 acc[4][4];
    #pragma unroll
    for (int i = 0; i < 4; ++i)
        #pragma unroll
        for (int j = 0; j < 4; ++j)
            #pragma unroll
            for (int r = 0; r < 4; ++r) acc[i][j][r] = 0.f;

    const int r0 = tid >> 2;
    const int c0 = tid & 3;
    const int rA = wm + (lane & 15);
    const int rB = wn + (lane & 15);
    const int co = (lane >> 4) * 8;

    auto STAGE = [&](int buf, int k0) {
        gload16(&sA[buf][(size_t)tid * 8],         &A[(size_t)(m0 + r0)      * K + k0 + c0 * 8]);
        gload16(&sA[buf][(size_t)(tid + 256) * 8], &A[(size_t)(m0 + r0 + 64) * K + k0 + c0 * 8]);
        gload16(&sB[buf][(size_t)tid * 8],         &B[(size_t)(n0 + r0)      * K + k0 + c0 * 8]);
        gload16(&sB[buf][(size_t)(tid + 256) * 8], &B[(size_t)(n0 + r0 + 64) * K + k0 + c0 * 8]);
    };

    STAGE(0, kbeg);
    STAGE(1, kbeg + BK);
    int kt = 0;
    for (int k0 = kbeg; k0 < kend; k0 += BK, ++kt) {
        if (k0 + BK >= kend) { PIPE_WAIT("0"); }
        else                 { PIPE_WAIT("4"); }
        if (k0 + 2 * BK < kend) STAGE((kt + 2) % 3, k0 + 2 * BK);

        const u16* cA = sA[kt % 3];
        const u16* cB = sB[kt % 3];
        bf16x8 ah[4], bh[4];
        #pragma unroll
        for (int i = 0; i < 4; ++i)
            ah[i] = *reinterpret_cast<const bf16x8*>(&cA[(size_t)(rA + i * 16) * BK + co]);
        #pragma unroll
        for (int j = 0; j < 4; ++j)
            bh[j] = *reinterpret_cast<const bf16x8*>(&cB[(size_t)(rB + j * 16) * BK + co]);
        #pragma unroll
        for (int i = 0; i < 4; ++i)
            #pragma unroll
            for (int j = 0; j < 4; ++j)
                acc[i][j] = __builtin_amdgcn_mfma_f32_16x16x32_bf16(ah[i], bh[j], acc[i][j], 0, 0, 0);
    }

    float* Cz = Cp + (size_t)z * M * N;
    const int crow0 = m0 + wm + (lane >> 4) * 4;
    const int ccol0 = n0 + wn + (lane & 15);
    #pragma unroll
    for (int i = 0; i < 4; ++i)
        #pragma unroll
        for (int j = 0; j < 4; ++j)
            #pragma unroll
            for (int r = 0; r < 4; ++r)
                Cz[(size_t)(crow0 + i * 16 + r) * N + ccol0 + j * 16] = acc[i][j][r];
}

// ---------------------------------------------------------------------------
// 64x128 tile bf16 GEMM (NT), BK=32, split-K, XCD-swizzled, 3-buffer
// counted-vmcnt pipeline. (out-projection)
// ---------------------------------------------------------------------------
__global__ __launch_bounds__(256)
void gemm64_kernel(const u16* __restrict__ A, const u16* __restrict__ B,
                   float* __restrict__ Cp, int M, int N, int K,
                   int nx, int ny, int nz)
{
    __shared__ __align__(16) u16 sA[3][64 * BK], sB[3][128 * BK];  // 36KB

    const int nwg = nx * ny * nz;
    const int wg  = xcd_swz(blockIdx.x, nwg);
    const int x   = wg % nx;
    const int y   = (wg / nx) % ny;
    const int z   = wg / (nx * ny);

    const int tid  = threadIdx.x;
    const int lane = tid & 63;
    const int wid  = tid >> 6;
    const int m0   = y * 64;
    const int n0   = x * 128;
    const int kc   = K / nz;
    const int kbeg = z * kc;
    const int kend = kbeg + kc;

    const int wm = (wid >> 1) * 32;
    const int wn = (wid & 1) * 64;
    const int g  = lane >> 4;
    const int li = lane & 15;

    f32x4 acc[2][4];
    #pragma unroll
    for (int i = 0; i < 2; ++i)
        #pragma unroll
        for (int j = 0; j < 4; ++j)
            #pragma unroll
            for (int r = 0; r < 4; ++r) acc[i][j][r] = 0.f;

    const int r0 = tid >> 2;
    const int c0 = (tid & 3) * 8;

    auto STAGE = [&](int buf, int k0) {
        gload16(&sA[buf][(size_t)tid * 8],         &A[(size_t)(m0 + r0)      * K + k0 + c0]);
        gload16(&sB[buf][(size_t)tid * 8],         &B[(size_t)(n0 + r0)      * K + k0 + c0]);
        gload16(&sB[buf][(size_t)(tid + 256) * 8], &B[(size_t)(n0 + r0 + 64) * K + k0 + c0]);
    };

    STAGE(0, kbeg);
    STAGE(1, kbeg + BK);
    int kt = 0;
    for (int k0 = kbeg; k0 < kend; k0 += BK, ++kt) {
        if (k0 + BK >= kend) { PIPE_WAIT("0"); }
        else                 { PIPE_WAIT("3"); }
        if (k0 + 2 * BK < kend) STAGE((kt + 2) % 3, k0 + 2 * BK);

        const u16* cA = sA[kt % 3];
        const u16* cB = sB[kt % 3];
        bf16x8 ah[2], bh[4];
        #pragma unroll
        for (int i = 0; i < 2; ++i)
            ah[i] = *reinterpret_cast<const bf16x8*>(&cA[(size_t)(wm + 16 * i + li) * BK + g * 8]);
        #pragma unroll
        for (int j = 0; j < 4; ++j)
            bh[j] = *reinterpret_cast<const bf16x8*>(&cB[(size_t)(wn + 16 * j + li) * BK + g * 8]);
        #pragma unroll
        for (int i = 0; i < 2; ++i)
            #pragma unroll
            for (int j = 0; j < 4; ++j)
                acc[i][j] = __builtin_amdgcn_mfma_f32_16x16x32_bf16(ah[i], bh[j], acc[i][j], 0, 0, 0);
    }

    float* Cz = Cp + (size_t)z * M * N;
    const int crow0 = m0 + wm + g * 4;
    const int ccol0 = n0 + wn + li;
    #pragma unroll
    for (int i = 0; i < 2; ++i)
        #pragma unroll
        for (int j = 0; j < 4; ++j)
            #pragma unroll
            for (int r = 0; r < 4; ++r)
                Cz[(size_t)(crow0 + i * 16 + r) * N + ccol0 + j * 16] = acc[i][j][r];
}

// ---------------------------------------------------------------------------
// Q projection 128x128 tile with fused RoPE -> Q2 bf16 (pre-scaled QSCALE)
// XCD-swizzled 1D grid (576 = 72 n x 8 m, y-fastest), 3-buffer counted-vmcnt.
// ---------------------------------------------------------------------------
__global__ __launch_bounds__(256)
void gemm_q_rope_kernel(const u16* __restrict__ A, const u16* __restrict__ B,
                        const float* __restrict__ tab, u16* __restrict__ Q2)
{
    __shared__ __align__(16) u16 sA[3][BM * BK], sB[3][BN * BK];   // 48KB

    const int K = C_MODEL;
    const int wg = xcd_swz(blockIdx.x, 576);
    const int y  = wg & 7;           // m-tile (y-fastest)
    const int x  = wg >> 3;          // n-tile

    const int tid  = threadIdx.x;
    const int lane = tid & 63;
    const int wid  = tid >> 6;
    const int m0   = y * BM;
    const int n0   = x * BN;

    const int wm = (wid >> 1) * 64;
    const int wn = (wid & 1) * 64;
    const int g  = lane >> 4;
    const int li = lane & 15;

    f32x4 acc[4][4];
    #pragma unroll
    for (int i = 0; i < 4; ++i)
        #pragma unroll
        for (int j = 0; j < 4; ++j)
            #pragma unroll
            for (int r = 0; r < 4; ++r) acc[i][j][r] = 0.f;

    const int r0 = tid >> 2;
    const int c0 = tid & 3;
    const int rA = wm + li;
    const int rB = wn + li;
    const int co = g * 8;

    auto STAGE = [&](int buf, int k0) {
        gload16(&sA[buf][(size_t)tid * 8],         &A[(size_t)(m0 + r0)      * K + k0 + c0 * 8]);
        gload16(&sA[buf][(size_t)(tid + 256) * 8], &A[(size_t)(m0 + r0 + 64) * K + k0 + c0 * 8]);
        gload16(&sB[buf][(size_t)tid * 8],         &B[(size_t)(n0 + r0)      * K + k0 + c0 * 8]);
        gload16(&sB[buf][(size_t)(tid + 256) * 8], &B[(size_t)(n0 + r0 + 64) * K + k0 + c0 * 8]);
    };

    STAGE(0, 0);
    STAGE(1, BK);
    int kt = 0;
    for (int k0 = 0; k0 < K; k0 += BK, ++kt) {
        if (k0 + BK >= K) { PIPE_WAIT("0"); }
        else              { PIPE_WAIT("4"); }
        if (k0 + 2 * BK < K) STAGE((kt + 2) % 3, k0 + 2 * BK);

        const u16* cA = sA[kt % 3];
        const u16* cB = sB[kt % 3];
        bf16x8 ah[4], bh[4];
        #pragma unroll
        for (int i = 0; i < 4; ++i)
            ah[i] = *reinterpret_cast<const bf16x8*>(&cA[(size_t)(rA + i * 16) * BK + co]);
        #pragma unroll
        for (int j = 0; j < 4; ++j)
            bh[j] = *reinterpret_cast<const bf16x8*>(&cB[(size_t)(rB + j * 16) * BK + co]);
        #pragma unroll
        for (int i = 0; i < 4; ++i)
            #pragma unroll
            for (int j = 0; j < 4; ++j)
                acc[i][j] = __builtin_amdgcn_mfma_f32_16x16x32_bf16(ah[i], bh[j], acc[i][j], 0, 0, 0);
    }

    // rope epilogue: row t = m0+wm+i*16+g*4+r, col n = n0+wn+j*16+li
    const int h  = (n0 + wn) >> 6;                 // head (fixed per wave)
    const bool ev = (li & 1) == 0;
    #pragma unroll
    for (int j = 0; j < 4; ++j) {
        const int e  = j * 16 + li;
        const int i2 = e >> 1;
        #pragma unroll
        for (int i = 0; i < 4; ++i) {
            #pragma unroll
            for (int r = 0; r < 4; ++r) {
                const int t = m0 + wm + i * 16 + g * 4 + r;
                const float own = acc[i][j][r];
                const float oth = __shfl_xor(own, 1);
                const float cs = tab[t * 64 + i2];
                const float sn = tab[t * 64 + 32 + i2];
                float o; int ch;
                if (ev) { o = own * cs - oth * sn; ch = i2; }
                else    { o = oth * sn + own * cs; ch = 32 + i2; }
                Q2[((size_t)h * T_SEQ + t) * 64 + ch] = tobf(o * QSCALE);
            }
        }
    }
}

// ---------------------------------------------------------------------------
// reduce split-K partials (out-proj)
// ---------------------------------------------------------------------------
__global__ __launch_bounds__(256)
void reduce_kernel(const float* __restrict__ part, float* __restrict__ out,
                   const float* __restrict__ bias, int MN, int N, int Z, float alpha)
{
    const int i = (blockIdx.x * 256 + threadIdx.x) * 4;
    if (i >= MN) return;
    float4 s = *reinterpret_cast<const float4*>(&part[i]);
    for (int z = 1; z < Z; ++z) {
        float4 p = *reinterpret_cast<const float4*>(&part[(size_t)z * MN + i]);
        s.x += p.x; s.y += p.y; s.z += p.z; s.w += p.w;
    }
    s.x *= alpha; s.y *= alpha; s.z *= alpha; s.w *= alpha;
    if (bias) {
        const int c = i % N;
        s.x += bias[c]; s.y += bias[c + 1]; s.z += bias[c + 2]; s.w += bias[c + 3];
    }
    *reinterpret_cast<float4*>(&out[i]) = s;
}

// reduce split-K partials for the fused K/V projection (bias select)
__global__ __launch_bounds__(256)
void reduce_kv_kernel(const float* __restrict__ part, float* __restrict__ out,
                      const float* __restrict__ kb, const float* __restrict__ vb,
                      int MN, int Z)
{
    const int i = (blockIdx.x * 256 + threadIdx.x) * 4;
    if (i >= MN) return;
    float4 s = *reinterpret_cast<const float4*>(&part[i]);
    for (int z = 1; z < Z; ++z) {
        float4 p = *reinterpret_cast<const float4*>(&part[(size_t)z * MN + i]);
        s.x += p.x; s.y += p.y; s.z += p.z; s.w += p.w;
    }
    const int c = i % 1536;
    const float* bp = (c < 768) ? (kb + c) : (vb + c - 768);
    s.x += bp[0]; s.y += bp[1]; s.z += bp[2]; s.w += bp[3];
    *reinterpret_cast<float4*>(&out[i]) = s;
}

// ---------------------------------------------------------------------------
// fold WQ (direct fp32 read): wqt[h*64+e][k] = sum_d Mt[h][e][d] * WQ[k][h*64+d]
// ---------------------------------------------------------------------------
__global__ __launch_bounds__(256)
void fold_wq_kernel(const float* __restrict__ WQ, const u16* __restrict__ Mth,
                    const u16* __restrict__ Mtl, u16* __restrict__ wqt)
{
    __shared__ __align__(16) u16 sMh[4096], sMl[4096];
    __shared__ __align__(16) u16 sB[8192];

    const int h   = blockIdx.x;
    const int k0  = blockIdx.y * 128;
    const int tid = threadIdx.x;
    const int lane = tid & 63, w = tid >> 6, g = lane >> 4, li = lane & 15;

    {
        const char* gmh = (const char*)(Mth + (size_t)h * 4096);
        const char* gml = (const char*)(Mtl + (size_t)h * 4096);
        #pragma unroll
        for (int p = 0; p < 2; ++p) {
            const int u = p * 256 + tid;
            const int row = u >> 3, off = (u & 7) * 16;
            const int src = swb(row, off);
            gload16((char*)sMh + u * 16, gmh + src);
            gload16((char*)sMl + u * 16, gml + src);
        }
    }
    {
        const int r    = tid >> 1;
        const int half = tid & 1;
        const float* src = WQ + (size_t)(k0 + r) * NQ + h * 64 + half * 32;
        #pragma unroll
        for (int q = 0; q < 8; ++q) {
            float4 v = *reinterpret_cast<const float4*>(&src[q * 4]);
            ushort4 o = { tobf(v.x), tobf(v.y), tobf(v.z), tobf(v.w) };
            const int byte = swb(r, half * 64 + q * 8);
            *reinterpret_cast<ushort4*>(reinterpret_cast<char*>(sB) + byte) = o;
        }
    }
    __syncthreads();

    f32x4 acc[4][2];
    #pragma unroll
    for (int i = 0; i < 4; ++i)
        #pragma unroll
        for (int jj = 0; jj < 2; ++jj)
            #pragma unroll
            for (int r = 0; r < 4; ++r) acc[i][jj][r] = 0.f;

    bf16x8 ah[4][2], al[4][2];
    #pragma unroll
    for (int i = 0; i < 4; ++i)
        #pragma unroll
        for (int ks = 0; ks < 2; ++ks) {
            ah[i][ks] = ldsr8(sMh, swb(16 * i + li, ks * 64 + g * 16));
            al[i][ks] = ldsr8(sMl, swb(16 * i + li, ks * 64 + g * 16));
        }
    #pragma unroll
    for (int jj = 0; jj < 2; ++jj) {
        const int brow = 16 * (2 * w + jj) + li;
        #pragma unroll
        for (int ks = 0; ks < 2; ++ks) {
            bf16x8 bh = ldsr8(sB, swb(brow, ks * 64 + g * 16));
            #pragma unroll
            for (int i = 0; i < 4; ++i) {
                acc[i][jj] = __builtin_amdgcn_mfma_f32_16x16x32_bf16(ah[i][ks], bh, acc[i][jj], 0, 0, 0);
                acc[i][jj] = __builtin_amdgcn_mfma_f32_16x16x32_bf16(al[i][ks], bh, acc[i][jj], 0, 0, 0);
            }
        }
    }

    #pragma unroll
    for (int i = 0; i < 4; ++i)
        #pragma unroll
        for (int jj = 0; jj < 2; ++jj) {
            const int kc = k0 + 16 * (2 * w + jj) + li;
            #pragma unroll
            for (int r = 0; r < 4; ++r) {
                const int e = 16 * i + g * 4 + r;
                wqt[((size_t)h * 64 + e) * 768 + kc] = tobf(acc[i][jj][r]);
            }
        }
}

// ---------------------------------------------------------------------------
// merged wedge+rope (K) / V-transpose kernel. grid (156, 16).
// ---------------------------------------------------------------------------
__global__ __launch_bounds__(256)
void wedge_vt_kernel(const float* __restrict__ KV, u16* __restrict__ K2,
                     u16* __restrict__ Vt,
                     const u16* __restrict__ Mth, const u16* __restrict__ Mtl,
                     const float* __restrict__ tab)
{
    __shared__ __align__(16) char smem[24576];
    const int b   = blockIdx.x;
    const int t0  = blockIdx.y * 64;
    const int tid = threadIdx.x;

    if (b < H_TOT) {
        u16* sX  = (u16*)smem;
        u16* sMh = (u16*)(smem + 8192);
        u16* sMl = (u16*)(smem + 16384);
        const int h = b;
        const int lane = tid & 63, w = tid >> 6, g = lane >> 4, li = lane & 15;

        {
            const int r  = tid >> 2;
            const int c0 = (tid & 3) * 16;
            const float* xrow = KV + (size_t)(t0 + r) * 1536 + (h % N_BR) * 64;
            #pragma unroll
            for (int q = 0; q < 4; ++q) {
                const int c = c0 + q * 4;
                float4 v = *reinterpret_cast<const float4*>(&xrow[c]);
                ushort4 hv = { tobf(v.x), tobf(v.y), tobf(v.z), tobf(v.w) };
                *reinterpret_cast<ushort4*>((char*)sX + swb(r, 2 * c)) = hv;
            }
        }
        {
            const char* gmh = (const char*)(Mth + (size_t)h * 4096);
            const char* gml = (const char*)(Mtl + (size_t)h * 4096);
            #pragma unroll
            for (int u = 0; u < 2; ++u) {
                const int L = (u * 256 + tid) * 16;
                const int row = L >> 7, off = L & 127;
                const int src = swb(row, off);
                gload16((char*)sMh + L, gmh + src);
                gload16((char*)sMl + L, gml + src);
            }
        }
        __syncthreads();

        f32x4 acc[4];
        #pragma unroll
        for (int j = 0; j < 4; ++j)
            #pragma unroll
            for (int r = 0; r < 4; ++r) acc[j][r] = 0.f;

        bf16x8 ah[2];
        #pragma unroll
        for (int ks = 0; ks < 2; ++ks)
            ah[ks] = ldsr8(sX, swb(w * 16 + li, ks * 64 + g * 16));
        #pragma unroll
        for (int ks = 0; ks < 2; ++ks)
            #pragma unroll
            for (int j = 0; j < 4; ++j) {
                bf16x8 bh = ldsr8(sMh, swb(16 * j + li, ks * 64 + g * 16));
                bf16x8 bl = ldsr8(sMl, swb(16 * j + li, ks * 64 + g * 16));
                acc[j] = __builtin_amdgcn_mfma_f32_16x16x32_bf16(ah[ks], bh, acc[j], 0, 0, 0);
                acc[j] = __builtin_amdgcn_mfma_f32_16x16x32_bf16(ah[ks], bl, acc[j], 0, 0, 0);
            }

        const bool ev = (li & 1) == 0;
        #pragma unroll
        for (int j = 0; j < 4; ++j) {
            const int e = 16 * j + li;
            const int i2 = e >> 1;
            #pragma unroll
            for (int r = 0; r < 4; ++r) {
                const int t = t0 + w * 16 + g * 4 + r;
                const float own = acc[j][r];
                const float oth = __shfl_xor(own, 1);
                const float cs = tab[t * 64 + i2];
                const float sn = tab[t * 64 + 32 + i2];
                float o; int ch;
                if (ev) { o = own * cs - oth * sn; ch = i2; }
                else    { o = oth * sn + own * cs; ch = 32 + i2; }
                K2[((size_t)h * T_SEQ + t) * 64 + ch] = tobf(o);
            }
        }
    } else {
        float (*Ls)[65] = (float (*)[65])smem;
        const int s = b - H_TOT;
        {
            const int r  = tid >> 2;
            const int c0 = (tid & 3) * 16;
            const float* row = KV + (size_t)(t0 + r) * 1536 + 768 + s * 64;
            #pragma unroll
            for (int q = 0; q < 4; ++q) {
                float4 v = *reinterpret_cast<const float4*>(&row[c0 + q * 4]);
                Ls[r][c0 + q * 4 + 0] = v.x; Ls[r][c0 + q * 4 + 1] = v.y;
                Ls[r][c0 + q * 4 + 2] = v.z; Ls[r][c0 + q * 4 + 3] = v.w;
            }
        }
        __syncthreads();
        {
            const int d  = tid >> 2;
            const int tq = (tid & 3) * 16;
            u16* orow = Vt + ((size_t)s * 64 + d) * T_SEQ + t0 + tq;
            #pragma unroll
            for (int q = 0; q < 4; ++q) {
                ushort4 o;
                o.x = tobf(Ls[tq + q * 4 + 0][d]);
                o.y = tobf(Ls[tq + q * 4 + 1][d]);
                o.z = tobf(Ls[tq + q * 4 + 2][d]);
                o.w = tobf(Ls[tq + q * 4 + 3][d]);
                *reinterpret_cast<ushort4*>(&orow[q * 4]) = o;
            }
        }
    }
}

// ---------------------------------------------------------------------------
// MFMA flash attention (unchanged from round 8)
// ---------------------------------------------------------------------------
__device__ __forceinline__ void attn_stage_kv(
    int buf, int kv0, int h, int s, int tid,
    const u16* __restrict__ K2, const u16* __restrict__ Vt,
    u16* sK, u16* sV)
{
    const char* gk = (const char*)(K2 + ((size_t)h * T_SEQ + kv0) * 64);
    const char* gv = (const char*)Vt + (size_t)s * 131072 + kv0 * 2;
    #pragma unroll
    for (int p = 0; p < 2; ++p) {
        const int u = p * 256 + tid;
        const int row = u >> 3;
        const int off = (u & 7) * 16;
        const int sw  = off ^ ((row & 7) << 4);
        const int j  = row >> 4, g2 = (row >> 2) & 3, rr = row & 3;
        const int srow = 32 * (j & 1) + 8 * g2 + 4 * (j >> 1) + rr;
        gload16((char*)sK + buf * 8192 + u * 16, gk + srow * 128 + sw);
        gload16((char*)sV + buf * 8192 + u * 16, gv + row * 2048 + sw);
    }
}

template<bool DIAG>
__device__ __forceinline__ void attn_tile_sw(
    int kv0, int qglob, int g, int li,
    const u16* sK, const u16* sV, const bf16x8* qa, const bf16x8 ones,
    f32x4* acc, f32x4& psacc)
{
    f32x4 sacc[4];
    #pragma unroll
    for (int j = 0; j < 4; ++j)
        #pragma unroll
        for (int r = 0; r < 4; ++r) sacc[j][r] = -SM_OFF * LOG2E;

    __builtin_amdgcn_s_setprio(1);
    #pragma unroll
    for (int ks = 0; ks < 2; ++ks)
        #pragma unroll
        for (int j = 0; j < 4; ++j) {
            bf16x8 kb = ldsr8(sK, swb(16 * j + li, ks * 64 + g * 16));
            sacc[j] = __builtin_amdgcn_mfma_f32_16x16x32_bf16(kb, qa[ks], sacc[j], 0, 0, 0);
        }
    __builtin_amdgcn_s_setprio(0);

    float p[4][4];
    const int kvb = kv0 + 8 * g;
    #pragma unroll
    for (int j = 0; j < 4; ++j)
        #pragma unroll
        for (int r = 0; r < 4; ++r) {
            float sv_ = sacc[j][r];
            if (DIAG) {
                const int kv = kvb + 32 * (j & 1) + 4 * (j >> 1) + r;
                if (kv > qglob) sv_ = -__builtin_inff();
            }
            p[j][r] = exp2raw(sv_);
        }

    __builtin_amdgcn_s_setprio(1);
    #pragma unroll
    for (int ks = 0; ks < 2; ++ks) {
        u32x4 pw;
        pw[0] = cvtpk(p[ks][0],     p[ks][1]);
        pw[1] = cvtpk(p[ks][2],     p[ks][3]);
        pw[2] = cvtpk(p[ks + 2][0], p[ks + 2][1]);
        pw[3] = cvtpk(p[ks + 2][2], p[ks + 2][3]);
        bf16x8 pa = __builtin_bit_cast(bf16x8, pw);
        psacc = __builtin_amdgcn_mfma_f32_16x16x32_bf16(ones, pa, psacc, 0, 0, 0);
        #pragma unroll
        for (int j = 0; j < 4; ++j) {
            bf16x8 vb = ldsr8(sV, swb(16 * j + li, ks * 64 + g * 16));
            acc[j] = __builtin_amdgcn_mfma_f32_16x16x32_bf16(vb, pa, acc[j], 0, 0, 0);
        }
    }
    __builtin_amdgcn_s_setprio(0);
}

__global__ __launch_bounds__(256)
void attn_mfma_kernel(const u16* __restrict__ Q2, const u16* __restrict__ K2,
                      const u16* __restrict__ Vt, const float* __restrict__ sink,
                      const float* __restrict__ v_nulls, u16* __restrict__ ctxb)
{
    const int h  = blockIdx.x;
    const int qt = 15 - (int)blockIdx.y;
    const int s  = h % N_BR;
    const int tid  = threadIdx.x;
    const int lane = tid & 63, w = tid >> 6, g = lane >> 4, li = lane & 15;

    __shared__ __align__(16) u16 sK[8192];
    __shared__ __align__(16) u16 sV[8192];

    const u16* qrow = Q2 + ((size_t)h * T_SEQ + qt * 64 + w * 16 + li) * 64;
    bf16x8 qa[2];
    qa[0] = *reinterpret_cast<const bf16x8*>(qrow + g * 8);
    qa[1] = *reinterpret_cast<const bf16x8*>(qrow + 32 + g * 8);

    bf16x8 ones;
    #pragma unroll
    for (int e = 0; e < 8; ++e) ones[e] = (__bf16)1.0f;

    attn_stage_kv(0, 0, h, s, tid, K2, Vt, sK, sV);

    f32x4 acc[4];
    #pragma unroll
    for (int j = 0; j < 4; ++j)
        #pragma unroll
        for (int r = 0; r < 4; ++r) acc[j][r] = 0.f;
    f32x4 psacc;
    #pragma unroll
    for (int r = 0; r < 4; ++r) psacc[r] = 0.f;

    __syncthreads();

    const int qglob = qt * 64 + w * 16 + li;
    const int nt = qt + 1;
    int cur = 0;
    for (int kt = 0; kt < nt - 1; ++kt) {
        attn_stage_kv(cur ^ 1, (kt + 1) * 64, h, s, tid, K2, Vt, sK, sV);
        attn_tile_sw<false>(kt * 64, qglob, g, li,
                            sK + cur * 4096, sV + cur * 4096, qa, ones, acc, psacc);
        __syncthreads();
        cur ^= 1;
    }
    attn_tile_sw<true>(qt * 64, qglob, g, li,
                       sK + cur * 4096, sV + cur * 4096, qa, ones, acc, psacc);

    const float es = __expf(sink[h] - SM_OFF);
    const float rz = 1.0f / (psacc[0] + es);

    const int t = qt * 64 + w * 16 + li;
    u16* orow = ctxb + (size_t)t * NQ + h * 64;
    const float* vn = v_nulls + h * 64;
    #pragma unroll
    for (int j = 0; j < 4; ++j) {
        const int d0 = 16 * j + 4 * g;
        float4 vnv = *reinterpret_cast<const float4*>(&vn[d0]);
        ushort4 o;
        o.x = tobf((acc[j][0] + es * vnv.x) * rz);
        o.y = tobf((acc[j][1] + es * vnv.y) * rz);
        o.z = tobf((acc[j][2] + es * vnv.z) * rz);
        o.w = tobf((acc[j][3] + es * vnv.w) * rz);
        *reinterpret_cast<ushort4*>(&orow[d0]) = o;
    }
}

// ---------------------------------------------------------------------------
// launcher
// ---------------------------------------------------------------------------
extern "C" void kernel_launch(void* const* d_in, const int* in_sizes, int n_in,
                              void* d_out, int out_size, void* d_ws, size_t ws_size,
                              hipStream_t stream)
{
    (void)in_sizes; (void)n_in; (void)out_size; (void)ws_size;

    const float* x       = (const float*)d_in[0];
    const float* WV_w    = (const float*)d_in[1];
    const float* WV_b    = (const float*)d_in[2];
    const float* WK_w    = (const float*)d_in[3];
    const float* WK_b    = (const float*)d_in[4];
    const float* WQ_w    = (const float*)d_in[5];
    const float* Amat    = (const float*)d_in[6];
    const float* id_bias = (const float*)d_in[7];
    const float* sink    = (const float*)d_in[8];
    const float* v_nulls = (const float*)d_in[9];
    const float* WO_w    = (const float*)d_in[10];
    const float* WO_b    = (const float*)d_in[11];
    float* out = (float*)d_out;

    // ---- workspace carve ----
    float* tab    = (float*)d_ws;            // 65536 f
    float* mbias  = tab + 65536;             // 768 f
    float* kvbase = mbias + 768;             // 1572864 f : [1024][1536] K|V
    u16* Mth  = (u16*)(kvbase + 1572864);    // 589824
    u16* Mtl  = Mth + 589824;                // 589824
    u16* xh   = Mtl + 589824;                // 786432
    u16* wqt  = xh + 786432;                 // 7077888 (folded WQ^T bf16)
    u16* wkvt = wqt + 7077888;               // 1179648 ([WK^T|WV^T] bf16)
    u16* wot  = wkvt + 1179648;              // 7077888 (WO^T bf16)
    u16* K2   = wot + 7077888;               // 9437184
    u16* Vt   = K2 + 9437184;                // 786432
    u16* Q2   = Vt + 786432;                 // 9437184
    u16* ctxb = Q2 + 9437184;                // 9437184
    float* pkv = (float*)(ctxb + 9437184);   // 6291456 f (KV partials Z=4)

    // out-proj partials Z=8 (25.2 MB) overlay K2+Vt+Q2 (39.3 MB, dead post-attn)
    float* outpart = (float*)K2;

    const dim3 blk(256);

    // 1) mega prep: tables, M, mean-bias, x->bf16, W transposes
    prep_kernel<<<dim3(9107), blk, 0, stream>>>(
        x, xh, Amat, id_bias, Mth, Mtl, WO_b, mbias, tab, WO_w, wot, WK_w, WV_w, wkvt);

    // 2) fold M into WQ -> W'Q^T bf16
    fold_wq_kernel<<<dim3(H_TOT, 6), blk, 0, stream>>>(WQ_w, Mth, Mtl, wqt);

    // 3) fused K/V projection, split-K=4, XCD-swizzled + pipelined (384 blocks)
    gemm_bf16_kernel<<<dim3(384), blk, 0, stream>>>(
        xh, wkvt, pkv, T_SEQ, 1536, C_MODEL, 12, 8, 4);
    reduce_kv_kernel<<<dim3(1536), blk, 0, stream>>>(pkv, kvbase, WK_b, WV_b, 1572864, 4);

    // 4) merged wedge+rope K -> K2 and V transpose -> Vt
    wedge_vt_kernel<<<dim3(156, 16), blk, 0, stream>>>(
        kvbase, K2, Vt, Mth, Mtl, tab);

    // 5) Q projection with fused rope -> Q2 (128^2 tiles, pipelined, 576 blocks)
    gemm_q_rope_kernel<<<dim3(576), blk, 0, stream>>>(xh, wqt, tab, Q2);

    // 6) flash attention (swapped/permuted, exp2, dbuf) -> ctx bf16
    attn_mfma_kernel<<<dim3(H_TOT, 16), blk, 0, stream>>>(
        Q2, K2, Vt, sink, v_nulls, ctxb);

    // 7) output projection: 64x128 tiles, split-K=8, pipelined (768 blocks)
    gemm64_kernel<<<dim3(768), blk, 0, stream>>>(
        ctxb, wot, outpart, T_SEQ, C_MODEL, NQ, 6, 16, 8);
    reduce_kernel<<<dim3(768), blk, 0, stream>>>(
        outpart, out, mbias, 786432, C_MODEL, 8, 1.0f / 12.0f);
}

// Round 11
// 160.397 us; speedup vs baseline: 1.1550x; 1.1550x over previous
//
#include <hip/hip_runtime.h>
#include <hip/hip_bf16.h>

// Problem constants (B=1)
#define T_SEQ   1024
#define C_MODEL 768
#define N_BR    12
#define DH      64
#define H_TOT   144          // N_BR * N_BR
#define NQ      9216         // C_MODEL * N_BR

typedef __bf16 bf16x8 __attribute__((ext_vector_type(8)));
typedef float  f32x4  __attribute__((ext_vector_type(4)));
typedef unsigned int u32x4 __attribute__((ext_vector_type(4)));
typedef unsigned short u16;

// fixed softmax offset (scores ~N(0,0.3); exact softmax for any offset)
#define SM_OFF 3.0f
#define LOG2E  1.44269504089f
#define QSCALE (0.125f * LOG2E)     // folded into Q: scores come out in log2 units

// ---------------------------------------------------------------------------
// helpers
// ---------------------------------------------------------------------------
__device__ __forceinline__ void gload16(void* lds, const void* g)
{
    __builtin_amdgcn_global_load_lds(
        (const __attribute__((address_space(1))) void*)g,
        (__attribute__((address_space(3))) void*)lds, 16, 0, 0);
}

__device__ __forceinline__ void split1(float x, u16& h, u16& l)
{
    __bf16 bh = (__bf16)x;
    __bf16 bl = (__bf16)(x - (float)bh);
    h = __builtin_bit_cast(u16, bh);
    l = __builtin_bit_cast(u16, bl);
}

__device__ __forceinline__ u16 tobf(float x)
{
    return __builtin_bit_cast(u16, (__bf16)x);
}

// packed f32x2 -> bf16x2 (low = a, high = b)
__device__ __forceinline__ unsigned cvtpk(float a, float b)
{
    unsigned r;
    asm("v_cvt_pk_bf16_f32 %0, %1, %2" : "=v"(r) : "v"(a), "v"(b));
    return r;
}

// raw v_exp_f32: 2^x
__device__ __forceinline__ float exp2raw(float x)
{
    float r;
    asm("v_exp_f32 %0, %1" : "=v"(r) : "v"(x));
    return r;
}

// bijective XCD swizzle (requires nwg % 8 == 0)
__device__ __forceinline__ int xcd_swz(int bid, int nwg)
{
    return (bid & 7) * (nwg >> 3) + (bid >> 3);
}

// swizzled LDS byte address for 128B-row tiles
__device__ __forceinline__ int swb(int row, int byteoff)
{
    return row * 128 + (byteoff ^ ((row & 7) << 4));
}

__device__ __forceinline__ bf16x8 ldsr8(const u16* p, int byteoff)
{
    return *reinterpret_cast<const bf16x8*>(reinterpret_cast<const char*>(p) + byteoff);
}

// ---------------------------------------------------------------------------
// mega prep kernel: rope table + M build + mean bias + x->bf16 + W transposes
// ---------------------------------------------------------------------------
__device__ __forceinline__ void convt_body(const float* __restrict__ W,
                                           u16* __restrict__ out, int K, int N,
                                           int nx, int ky, float (*t)[33], int tid)
{
    const int n0 = nx * 32;
    const int k0 = ky * 32;
    const int tx = tid & 31;
    const int ty = tid >> 5;
    #pragma unroll
    for (int r = 0; r < 4; ++r)
        t[ty + r * 8][tx] = W[(size_t)(k0 + ty + r * 8) * N + n0 + tx];
    __syncthreads();
    #pragma unroll
    for (int r = 0; r < 4; ++r)
        out[(size_t)(n0 + ty + r * 8) * K + k0 + tx] = tobf(t[tx][ty + r * 8]);
}

__global__ __launch_bounds__(256)
void prep_kernel(const float* __restrict__ x, u16* __restrict__ xh,
                 const float* __restrict__ Amat, const float* __restrict__ id_bias,
                 u16* __restrict__ Mth, u16* __restrict__ Mtl,
                 const float* __restrict__ WO_b, float* __restrict__ mbias,
                 float* __restrict__ tab,
                 const float* __restrict__ WO_w, u16* __restrict__ wot,
                 const float* __restrict__ WK_w, const float* __restrict__ WV_w,
                 u16* __restrict__ wkvt)
{
    __shared__ float tsh[32][33];
    const int b   = blockIdx.x;
    const int tid = threadIdx.x;

    if (b < 128) {                       // rope cos/sin table
        const int idx = b * 256 + tid;
        const int t = idx >> 5, i = idx & 31;
        const float inv = expf(-(float)i * (logf(10000.f) / 32.f));
        const float fr = (float)t * inv;
        tab[t * 64 + i]      = cosf(fr);
        tab[t * 64 + 32 + i] = sinf(fr);
    } else if (b < 272) {                // per-head M^T (hi/lo)
        const int h = b - 128;
        const int base = tid * 16;
        #pragma unroll
        for (int i = 0; i < 16; ++i) {
            const int idx = base + i;
            const int e = idx >> 6, d = idx & 63;
            float v = Amat[d * 64 + e] - Amat[e * 64 + d];
            if (d == e) v += 1.0f + id_bias[h * 64 + d];
            u16 hh, ll;
            split1(v, hh, ll);
            Mth[(size_t)h * 4096 + idx] = hh;
            Mtl[(size_t)h * 4096 + idx] = ll;
        }
    } else if (b < 275) {                // mean of WO_b
        const int d = (b - 272) * 256 + tid;
        if (d < C_MODEL) {
            float s = 0.f;
            #pragma unroll
            for (int n = 0; n < N_BR; ++n) s += WO_b[n * C_MODEL + d];
            mbias[d] = s * (1.0f / 12.0f);
        }
    } else if (b < 1043) {               // x -> bf16
        const size_t i = (size_t)(b - 275) * 1024 + tid * 4;
        float4 v = *reinterpret_cast<const float4*>(&x[i]);
        ushort4 o = { tobf(v.x), tobf(v.y), tobf(v.z), tobf(v.w) };
        *reinterpret_cast<ushort4*>(&xh[i]) = o;
    } else if (b < 7955) {               // WO^T bf16 [768][9216]
        const int u = b - 1043;
        convt_body(WO_w, wot, NQ, C_MODEL, u % 24, u / 24, tsh, tid);
    } else if (b < 8531) {               // WK^T bf16 [768][768]
        const int u = b - 7955;
        convt_body(WK_w, wkvt, C_MODEL, C_MODEL, u % 24, u / 24, tsh, tid);
    } else {                             // WV^T bf16 [768][768]
        const int u = b - 8531;
        convt_body(WV_w, wkvt + 589824, C_MODEL, C_MODEL, u % 24, u / 24, tsh, tid);
    }
}

// ---------------------------------------------------------------------------
// plain-bf16 MFMA GEMM (NT), 128x128 tile, BK=32, split-K, XCD-swizzled,
// split-barrier depth-2 pipeline (2 buffers, counted vmcnt, no sched pin).
// (K/V projection; 4 loads/stage)
// ---------------------------------------------------------------------------
#define BM 128
#define BN 128
#define BK 32

__global__ __launch_bounds__(256)
void gemm_bf16_kernel(const u16* __restrict__ A, const u16* __restrict__ B,
                      float* __restrict__ Cp, int M, int N, int K,
                      int nx, int ny, int nz)
{
    __shared__ __align__(16) u16 sA[2][BM * BK], sB[2][BN * BK];   // 32KB

    const int nwg = nx * ny * nz;
    const int wg  = xcd_swz(blockIdx.x, nwg);
    const int x   = wg % nx;
    const int y   = (wg / nx) % ny;
    const int z   = wg / (nx * ny);

    const int tid  = threadIdx.x;
    const int lane = tid & 63;
    const int wid  = tid >> 6;
    const int m0   = y * BM;
    const int n0   = x * BN;
    const int kc   = K / nz;
    const int kbeg = z * kc;
    const int kend = kbeg + kc;

    const int wm = (wid >> 1) * 64;
    const int wn = (wid & 1) * 64;

    f32x4 acc[4][4];
    #pragma unroll
    for (int i = 0; i < 4; ++i)
        #pragma unroll
        for (int j = 0; j < 4; ++j)
            #pragma unroll
            for (int r = 0; r < 4; ++r) acc[i][j][r] = 0.f;

    const int r0 = tid >> 2;
    const int c0 = tid & 3;
    const int rA = wm + (lane & 15);
    const int rB = wn + (lane & 15);
    const int co = (lane >> 4) * 8;

    auto STAGE = [&](int buf, int k0) {
        gload16(&sA[buf][(size_t)tid * 8],         &A[(size_t)(m0 + r0)      * K + k0 + c0 * 8]);
        gload16(&sA[buf][(size_t)(tid + 256) * 8], &A[(size_t)(m0 + r0 + 64) * K + k0 + c0 * 8]);
        gload16(&sB[buf][(size_t)tid * 8],         &B[(size_t)(n0 + r0)      * K + k0 + c0 * 8]);
        gload16(&sB[buf][(size_t)(tid + 256) * 8], &B[(size_t)(n0 + r0 + 64) * K + k0 + c0 * 8]);
    };

    STAGE(0, kbeg);
    if (kbeg + BK < kend) STAGE(1, kbeg + BK);
    int cur = 0;
    for (int k0 = kbeg; k0 < kend; k0 += BK) {
        // wait own stage(kt); keep stage(kt+1) in flight (4 loads)
        if (k0 + BK >= kend) { asm volatile("s_waitcnt vmcnt(0)" ::: "memory"); }
        else                 { asm volatile("s_waitcnt vmcnt(4)" ::: "memory"); }
        __builtin_amdgcn_s_barrier();        // all waves' stage(kt) landed

        bf16x8 ah[4], bh[4];
        #pragma unroll
        for (int i = 0; i < 4; ++i)
            ah[i] = *reinterpret_cast<const bf16x8*>(&sA[cur][(size_t)(rA + i * 16) * BK + co]);
        #pragma unroll
        for (int j = 0; j < 4; ++j)
            bh[j] = *reinterpret_cast<const bf16x8*>(&sB[cur][(size_t)(rB + j * 16) * BK + co]);
        #pragma unroll
        for (int i = 0; i < 4; ++i)
            #pragma unroll
            for (int j = 0; j < 4; ++j)
                acc[i][j] = __builtin_amdgcn_mfma_f32_16x16x32_bf16(ah[i], bh[j], acc[i][j], 0, 0, 0);

        __builtin_amdgcn_s_barrier();        // all waves done reading buf cur
        if (k0 + 2 * BK < kend) STAGE(cur, k0 + 2 * BK);
        cur ^= 1;
    }

    float* Cz = Cp + (size_t)z * M * N;
    const int crow0 = m0 + wm + (lane >> 4) * 4;
    const int ccol0 = n0 + wn + (lane & 15);
    #pragma unroll
    for (int i = 0; i < 4; ++i)
        #pragma unroll
        for (int j = 0; j < 4; ++j)
            #pragma unroll
            for (int r = 0; r < 4; ++r)
                Cz[(size_t)(crow0 + i * 16 + r) * N + ccol0 + j * 16] = acc[i][j][r];
}

// ---------------------------------------------------------------------------
// 64x128 tile bf16 GEMM (NT), BK=32, split-K, XCD-swizzled, split-barrier
// depth-2 pipeline (3 loads/stage). (out-projection)
// ---------------------------------------------------------------------------
__global__ __launch_bounds__(256)
void gemm64_kernel(const u16* __restrict__ A, const u16* __restrict__ B,
                   float* __restrict__ Cp, int M, int N, int K,
                   int nx, int ny, int nz)
{
    __shared__ __align__(16) u16 sA[2][64 * BK], sB[2][128 * BK];  // 24KB

    const int nwg = nx * ny * nz;
    const int wg  = xcd_swz(blockIdx.x, nwg);
    const int x   = wg % nx;
    const int y   = (wg / nx) % ny;
    const int z   = wg / (nx * ny);

    const int tid  = threadIdx.x;
    const int lane = tid & 63;
    const int wid  = tid >> 6;
    const int m0   = y * 64;
    const int n0   = x * 128;
    const int kc   = K / nz;
    const int kbeg = z * kc;
    const int kend = kbeg + kc;

    const int wm = (wid >> 1) * 32;
    const int wn = (wid & 1) * 64;
    const int g  = lane >> 4;
    const int li = lane & 15;

    f32x4 acc[2][4];
    #pragma unroll
    for (int i = 0; i < 2; ++i)
        #pragma unroll
        for (int j = 0; j < 4; ++j)
            #pragma unroll
            for (int r = 0; r < 4; ++r) acc[i][j][r] = 0.f;

    const int r0 = tid >> 2;
    const int c0 = (tid & 3) * 8;

    auto STAGE = [&](int buf, int k0) {
        gload16(&sA[buf][(size_t)tid * 8],         &A[(size_t)(m0 + r0)      * K + k0 + c0]);
        gload16(&sB[buf][(size_t)tid * 8],         &B[(size_t)(n0 + r0)      * K + k0 + c0]);
        gload16(&sB[buf][(size_t)(tid + 256) * 8], &B[(size_t)(n0 + r0 + 64) * K + k0 + c0]);
    };

    STAGE(0, kbeg);
    if (kbeg + BK < kend) STAGE(1, kbeg + BK);
    int cur = 0;
    for (int k0 = kbeg; k0 < kend; k0 += BK) {
        if (k0 + BK >= kend) { asm volatile("s_waitcnt vmcnt(0)" ::: "memory"); }
        else                 { asm volatile("s_waitcnt vmcnt(3)" ::: "memory"); }
        __builtin_amdgcn_s_barrier();

        bf16x8 ah[2], bh[4];
        #pragma unroll
        for (int i = 0; i < 2; ++i)
            ah[i] = *reinterpret_cast<const bf16x8*>(&sA[cur][(size_t)(wm + 16 * i + li) * BK + g * 8]);
        #pragma unroll
        for (int j = 0; j < 4; ++j)
            bh[j] = *reinterpret_cast<const bf16x8*>(&sB[cur][(size_t)(wn + 16 * j + li) * BK + g * 8]);
        #pragma unroll
        for (int i = 0; i < 2; ++i)
            #pragma unroll
            for (int j = 0; j < 4; ++j)
                acc[i][j] = __builtin_amdgcn_mfma_f32_16x16x32_bf16(ah[i], bh[j], acc[i][j], 0, 0, 0);

        __builtin_amdgcn_s_barrier();
        if (k0 + 2 * BK < kend) STAGE(cur, k0 + 2 * BK);
        cur ^= 1;
    }

    float* Cz = Cp + (size_t)z * M * N;
    const int crow0 = m0 + wm + g * 4;
    const int ccol0 = n0 + wn + li;
    #pragma unroll
    for (int i = 0; i < 2; ++i)
        #pragma unroll
        for (int j = 0; j < 4; ++j)
            #pragma unroll
            for (int r = 0; r < 4; ++r)
                Cz[(size_t)(crow0 + i * 16 + r) * N + ccol0 + j * 16] = acc[i][j][r];
}

// ---------------------------------------------------------------------------
// Q projection 64x128 tile with fused RoPE -> Q2 bf16 (pre-scaled QSCALE)
// XCD-swizzled 1D grid (1152, y-fastest), split-barrier depth-2 pipeline.
// ---------------------------------------------------------------------------
__global__ __launch_bounds__(256)
void gemm_q_rope_kernel(const u16* __restrict__ A, const u16* __restrict__ B,
                        const float* __restrict__ tab, u16* __restrict__ Q2)
{
    __shared__ __align__(16) u16 sA[2][64 * BK], sB[2][128 * BK];  // 24KB

    const int K = C_MODEL;
    const int wg = xcd_swz(blockIdx.x, 1152);
    const int y  = wg & 15;          // m-tile (y-fastest)
    const int x  = wg >> 4;          // n-tile

    const int tid  = threadIdx.x;
    const int lane = tid & 63;
    const int wid  = tid >> 6;
    const int m0   = y * 64;
    const int n0   = x * 128;

    const int wm = (wid >> 1) * 32;
    const int wn = (wid & 1) * 64;
    const int g  = lane >> 4;
    const int li = lane & 15;

    f32x4 acc[2][4];
    #pragma unroll
    for (int i = 0; i < 2; ++i)
        #pragma unroll
        for (int j = 0; j < 4; ++j)
            #pragma unroll
            for (int r = 0; r < 4; ++r) acc[i][j][r] = 0.f;

    const int r0 = tid >> 2;
    const int c0 = (tid & 3) * 8;

    auto STAGE = [&](int buf, int k0) {
        gload16(&sA[buf][(size_t)tid * 8],         &A[(size_t)(m0 + r0)      * K + k0 + c0]);
        gload16(&sB[buf][(size_t)tid * 8],         &B[(size_t)(n0 + r0)      * K + k0 + c0]);
        gload16(&sB[buf][(size_t)(tid + 256) * 8], &B[(size_t)(n0 + r0 + 64) * K + k0 + c0]);
    };

    STAGE(0, 0);
    STAGE(1, BK);
    int cur = 0;
    for (int k0 = 0; k0 < K; k0 += BK) {
        if (k0 + BK >= K) { asm volatile("s_waitcnt vmcnt(0)" ::: "memory"); }
        else              { asm volatile("s_waitcnt vmcnt(3)" ::: "memory"); }
        __builtin_amdgcn_s_barrier();

        bf16x8 ah[2], bh[4];
        #pragma unroll
        for (int i = 0; i < 2; ++i)
            ah[i] = *reinterpret_cast<const bf16x8*>(&sA[cur][(size_t)(wm + 16 * i + li) * BK + g * 8]);
        #pragma unroll
        for (int j = 0; j < 4; ++j)
            bh[j] = *reinterpret_cast<const bf16x8*>(&sB[cur][(size_t)(wn + 16 * j + li) * BK + g * 8]);
        #pragma unroll
        for (int i = 0; i < 2; ++i)
            #pragma unroll
            for (int j = 0; j < 4; ++j)
                acc[i][j] = __builtin_amdgcn_mfma_f32_16x16x32_bf16(ah[i], bh[j], acc[i][j], 0, 0, 0);

        __builtin_amdgcn_s_barrier();
        if (k0 + 2 * BK < K) STAGE(cur, k0 + 2 * BK);
        cur ^= 1;
    }

    const int h  = (n0 + wn) >> 6;
    const bool ev = (li & 1) == 0;
    #pragma unroll
    for (int j = 0; j < 4; ++j) {
        const int e  = j * 16 + li;
        const int i2 = e >> 1;
        #pragma unroll
        for (int i = 0; i < 2; ++i) {
            #pragma unroll
            for (int r = 0; r < 4; ++r) {
                const int t = m0 + wm + i * 16 + g * 4 + r;
                const float own = acc[i][j][r];
                const float oth = __shfl_xor(own, 1);
                const float cs = tab[t * 64 + i2];
                const float sn = tab[t * 64 + 32 + i2];
                float o; int ch;
                if (ev) { o = own * cs - oth * sn; ch = i2; }
                else    { o = oth * sn + own * cs; ch = 32 + i2; }
                Q2[((size_t)h * T_SEQ + t) * 64 + ch] = tobf(o * QSCALE);
            }
        }
    }
}

// ---------------------------------------------------------------------------
// reduce split-K partials (out-proj)
// ---------------------------------------------------------------------------
__global__ __launch_bounds__(256)
void reduce_kernel(const float* __restrict__ part, float* __restrict__ out,
                   const float* __restrict__ bias, int MN, int N, int Z, float alpha)
{
    const int i = (blockIdx.x * 256 + threadIdx.x) * 4;
    if (i >= MN) return;
    float4 s = *reinterpret_cast<const float4*>(&part[i]);
    for (int z = 1; z < Z; ++z) {
        float4 p = *reinterpret_cast<const float4*>(&part[(size_t)z * MN + i]);
        s.x += p.x; s.y += p.y; s.z += p.z; s.w += p.w;
    }
    s.x *= alpha; s.y *= alpha; s.z *= alpha; s.w *= alpha;
    if (bias) {
        const int c = i % N;
        s.x += bias[c]; s.y += bias[c + 1]; s.z += bias[c + 2]; s.w += bias[c + 3];
    }
    *reinterpret_cast<float4*>(&out[i]) = s;
}

// reduce split-K partials for the fused K/V projection (bias select)
__global__ __launch_bounds__(256)
void reduce_kv_kernel(const float* __restrict__ part, float* __restrict__ out,
                      const float* __restrict__ kb, const float* __restrict__ vb,
                      int MN, int Z)
{
    const int i = (blockIdx.x * 256 + threadIdx.x) * 4;
    if (i >= MN) return;
    float4 s = *reinterpret_cast<const float4*>(&part[i]);
    for (int z = 1; z < Z; ++z) {
        float4 p = *reinterpret_cast<const float4*>(&part[(size_t)z * MN + i]);
        s.x += p.x; s.y += p.y; s.z += p.z; s.w += p.w;
    }
    const int c = i % 1536;
    const float* bp = (c < 768) ? (kb + c) : (vb + c - 768);
    s.x += bp[0]; s.y += bp[1]; s.z += bp[2]; s.w += bp[3];
    *reinterpret_cast<float4*>(&out[i]) = s;
}

// ---------------------------------------------------------------------------
// fold WQ (direct fp32 read): wqt[h*64+e][k] = sum_d Mt[h][e][d] * WQ[k][h*64+d]
// ---------------------------------------------------------------------------
__global__ __launch_bounds__(256)
void fold_wq_kernel(const float* __restrict__ WQ, const u16* __restrict__ Mth,
                    const u16* __restrict__ Mtl, u16* __restrict__ wqt)
{
    __shared__ __align__(16) u16 sMh[4096], sMl[4096];
    __shared__ __align__(16) u16 sB[8192];

    const int h   = blockIdx.x;
    const int k0  = blockIdx.y * 128;
    const int tid = threadIdx.x;
    const int lane = tid & 63, w = tid >> 6, g = lane >> 4, li = lane & 15;

    {
        const char* gmh = (const char*)(Mth + (size_t)h * 4096);
        const char* gml = (const char*)(Mtl + (size_t)h * 4096);
        #pragma unroll
        for (int p = 0; p < 2; ++p) {
            const int u = p * 256 + tid;
            const int row = u >> 3, off = (u & 7) * 16;
            const int src = swb(row, off);
            gload16((char*)sMh + u * 16, gmh + src);
            gload16((char*)sMl + u * 16, gml + src);
        }
    }
    {
        const int r    = tid >> 1;
        const int half = tid & 1;
        const float* src = WQ + (size_t)(k0 + r) * NQ + h * 64 + half * 32;
        #pragma unroll
        for (int q = 0; q < 8; ++q) {
            float4 v = *reinterpret_cast<const float4*>(&src[q * 4]);
            ushort4 o = { tobf(v.x), tobf(v.y), tobf(v.z), tobf(v.w) };
            const int byte = swb(r, half * 64 + q * 8);
            *reinterpret_cast<ushort4*>(reinterpret_cast<char*>(sB) + byte) = o;
        }
    }
    __syncthreads();

    f32x4 acc[4][2];
    #pragma unroll
    for (int i = 0; i < 4; ++i)
        #pragma unroll
        for (int jj = 0; jj < 2; ++jj)
            #pragma unroll
            for (int r = 0; r < 4; ++r) acc[i][jj][r] = 0.f;

    bf16x8 ah[4][2], al[4][2];
    #pragma unroll
    for (int i = 0; i < 4; ++i)
        #pragma unroll
        for (int ks = 0; ks < 2; ++ks) {
            ah[i][ks] = ldsr8(sMh, swb(16 * i + li, ks * 64 + g * 16));
            al[i][ks] = ldsr8(sMl, swb(16 * i + li, ks * 64 + g * 16));
        }
    #pragma unroll
    for (int jj = 0; jj < 2; ++jj) {
        const int brow = 16 * (2 * w + jj) + li;
        #pragma unroll
        for (int ks = 0; ks < 2; ++ks) {
            bf16x8 bh = ldsr8(sB, swb(brow, ks * 64 + g * 16));
            #pragma unroll
            for (int i = 0; i < 4; ++i) {
                acc[i][jj] = __builtin_amdgcn_mfma_f32_16x16x32_bf16(ah[i][ks], bh, acc[i][jj], 0, 0, 0);
                acc[i][jj] = __builtin_amdgcn_mfma_f32_16x16x32_bf16(al[i][ks], bh, acc[i][jj], 0, 0, 0);
            }
        }
    }

    #pragma unroll
    for (int i = 0; i < 4; ++i)
        #pragma unroll
        for (int jj = 0; jj < 2; ++jj) {
            const int kc = k0 + 16 * (2 * w + jj) + li;
            #pragma unroll
            for (int r = 0; r < 4; ++r) {
                const int e = 16 * i + g * 4 + r;
                wqt[((size_t)h * 64 + e) * 768 + kc] = tobf(acc[i][jj][r]);
            }
        }
}

// ---------------------------------------------------------------------------
// merged wedge+rope (K) / V-transpose kernel. grid (156, 16).
// ---------------------------------------------------------------------------
__global__ __launch_bounds__(256)
void wedge_vt_kernel(const float* __restrict__ KV, u16* __restrict__ K2,
                     u16* __restrict__ Vt,
                     const u16* __restrict__ Mth, const u16* __restrict__ Mtl,
                     const float* __restrict__ tab)
{
    __shared__ __align__(16) char smem[24576];
    const int b   = blockIdx.x;
    const int t0  = blockIdx.y * 64;
    const int tid = threadIdx.x;

    if (b < H_TOT) {
        u16* sX  = (u16*)smem;
        u16* sMh = (u16*)(smem + 8192);
        u16* sMl = (u16*)(smem + 16384);
        const int h = b;
        const int lane = tid & 63, w = tid >> 6, g = lane >> 4, li = lane & 15;

        {
            const int r  = tid >> 2;
            const int c0 = (tid & 3) * 16;
            const float* xrow = KV + (size_t)(t0 + r) * 1536 + (h % N_BR) * 64;
            #pragma unroll
            for (int q = 0; q < 4; ++q) {
                const int c = c0 + q * 4;
                float4 v = *reinterpret_cast<const float4*>(&xrow[c]);
                ushort4 hv = { tobf(v.x), tobf(v.y), tobf(v.z), tobf(v.w) };
                *reinterpret_cast<ushort4*>((char*)sX + swb(r, 2 * c)) = hv;
            }
        }
        {
            const char* gmh = (const char*)(Mth + (size_t)h * 4096);
            const char* gml = (const char*)(Mtl + (size_t)h * 4096);
            #pragma unroll
            for (int u = 0; u < 2; ++u) {
                const int L = (u * 256 + tid) * 16;
                const int row = L >> 7, off = L & 127;
                const int src = swb(row, off);
                gload16((char*)sMh + L, gmh + src);
                gload16((char*)sMl + L, gml + src);
            }
        }
        __syncthreads();

        f32x4 acc[4];
        #pragma unroll
        for (int j = 0; j < 4; ++j)
            #pragma unroll
            for (int r = 0; r < 4; ++r) acc[j][r] = 0.f;

        bf16x8 ah[2];
        #pragma unroll
        for (int ks = 0; ks < 2; ++ks)
            ah[ks] = ldsr8(sX, swb(w * 16 + li, ks * 64 + g * 16));
        #pragma unroll
        for (int ks = 0; ks < 2; ++ks)
            #pragma unroll
            for (int j = 0; j < 4; ++j) {
                bf16x8 bh = ldsr8(sMh, swb(16 * j + li, ks * 64 + g * 16));
                bf16x8 bl = ldsr8(sMl, swb(16 * j + li, ks * 64 + g * 16));
                acc[j] = __builtin_amdgcn_mfma_f32_16x16x32_bf16(ah[ks], bh, acc[j], 0, 0, 0);
                acc[j] = __builtin_amdgcn_mfma_f32_16x16x32_bf16(ah[ks], bl, acc[j], 0, 0, 0);
            }

        const bool ev = (li & 1) == 0;
        #pragma unroll
        for (int j = 0; j < 4; ++j) {
            const int e = 16 * j + li;
            const int i2 = e >> 1;
            #pragma unroll
            for (int r = 0; r < 4; ++r) {
                const int t = t0 + w * 16 + g * 4 + r;
                const float own = acc[j][r];
                const float oth = __shfl_xor(own, 1);
                const float cs = tab[t * 64 + i2];
                const float sn = tab[t * 64 + 32 + i2];
                float o; int ch;
                if (ev) { o = own * cs - oth * sn; ch = i2; }
                else    { o = oth * sn + own * cs; ch = 32 + i2; }
                K2[((size_t)h * T_SEQ + t) * 64 + ch] = tobf(o);
            }
        }
    } else {
        float (*Ls)[65] = (float (*)[65])smem;
        const int s = b - H_TOT;
        {
            const int r  = tid >> 2;
            const int c0 = (tid & 3) * 16;
            const float* row = KV + (size_t)(t0 + r) * 1536 + 768 + s * 64;
            #pragma unroll
            for (int q = 0; q < 4; ++q) {
                float4 v = *reinterpret_cast<const float4*>(&row[c0 + q * 4]);
                Ls[r][c0 + q * 4 + 0] = v.x; Ls[r][c0 + q * 4 + 1] = v.y;
                Ls[r][c0 + q * 4 + 2] = v.z; Ls[r][c0 + q * 4 + 3] = v.w;
            }
        }
        __syncthreads();
        {
            const int d  = tid >> 2;
            const int tq = (tid & 3) * 16;
            u16* orow = Vt + ((size_t)s * 64 + d) * T_SEQ + t0 + tq;
            #pragma unroll
            for (int q = 0; q < 4; ++q) {
                ushort4 o;
                o.x = tobf(Ls[tq + q * 4 + 0][d]);
                o.y = tobf(Ls[tq + q * 4 + 1][d]);
                o.z = tobf(Ls[tq + q * 4 + 2][d]);
                o.w = tobf(Ls[tq + q * 4 + 3][d]);
                *reinterpret_cast<ushort4*>(&orow[q * 4]) = o;
            }
        }
    }
}

// ---------------------------------------------------------------------------
// MFMA flash attention (round-8 proven version, unchanged)
// ---------------------------------------------------------------------------
__device__ __forceinline__ void attn_stage_kv(
    int buf, int kv0, int h, int s, int tid,
    const u16* __restrict__ K2, const u16* __restrict__ Vt,
    u16* sK, u16* sV)
{
    const char* gk = (const char*)(K2 + ((size_t)h * T_SEQ + kv0) * 64);
    const char* gv = (const char*)Vt + (size_t)s * 131072 + kv0 * 2;
    #pragma unroll
    for (int p = 0; p < 2; ++p) {
        const int u = p * 256 + tid;
        const int row = u >> 3;
        const int off = (u & 7) * 16;
        const int sw  = off ^ ((row & 7) << 4);
        const int j  = row >> 4, g2 = (row >> 2) & 3, rr = row & 3;
        const int srow = 32 * (j & 1) + 8 * g2 + 4 * (j >> 1) + rr;
        gload16((char*)sK + buf * 8192 + u * 16, gk + srow * 128 + sw);
        gload16((char*)sV + buf * 8192 + u * 16, gv + row * 2048 + sw);
    }
}

template<bool DIAG>
__device__ __forceinline__ void attn_tile_sw(
    int kv0, int qglob, int g, int li,
    const u16* sK, const u16* sV, const bf16x8* qa, const bf16x8 ones,
    f32x4* acc, f32x4& psacc)
{
    f32x4 sacc[4];
    #pragma unroll
    for (int j = 0; j < 4; ++j)
        #pragma unroll
        for (int r = 0; r < 4; ++r) sacc[j][r] = -SM_OFF * LOG2E;

    __builtin_amdgcn_s_setprio(1);
    #pragma unroll
    for (int ks = 0; ks < 2; ++ks)
        #pragma unroll
        for (int j = 0; j < 4; ++j) {
            bf16x8 kb = ldsr8(sK, swb(16 * j + li, ks * 64 + g * 16));
            sacc[j] = __builtin_amdgcn_mfma_f32_16x16x32_bf16(kb, qa[ks], sacc[j], 0, 0, 0);
        }
    __builtin_amdgcn_s_setprio(0);

    float p[4][4];
    const int kvb = kv0 + 8 * g;
    #pragma unroll
    for (int j = 0; j < 4; ++j)
        #pragma unroll
        for (int r = 0; r < 4; ++r) {
            float sv_ = sacc[j][r];
            if (DIAG) {
                const int kv = kvb + 32 * (j & 1) + 4 * (j >> 1) + r;
                if (kv > qglob) sv_ = -__builtin_inff();
            }
            p[j][r] = exp2raw(sv_);
        }

    __builtin_amdgcn_s_setprio(1);
    #pragma unroll
    for (int ks = 0; ks < 2; ++ks) {
        u32x4 pw;
        pw[0] = cvtpk(p[ks][0],     p[ks][1]);
        pw[1] = cvtpk(p[ks][2],     p[ks][3]);
        pw[2] = cvtpk(p[ks + 2][0], p[ks + 2][1]);
        pw[3] = cvtpk(p[ks + 2][2], p[ks + 2][3]);
        bf16x8 pa = __builtin_bit_cast(bf16x8, pw);
        psacc = __builtin_amdgcn_mfma_f32_16x16x32_bf16(ones, pa, psacc, 0, 0, 0);
        #pragma unroll
        for (int j = 0; j < 4; ++j) {
            bf16x8 vb = ldsr8(sV, swb(16 * j + li, ks * 64 + g * 16));
            acc[j] = __builtin_amdgcn_mfma_f32_16x16x32_bf16(vb, pa, acc[j], 0, 0, 0);
        }
    }
    __builtin_amdgcn_s_setprio(0);
}

__global__ __launch_bounds__(256)
void attn_mfma_kernel(const u16* __restrict__ Q2, const u16* __restrict__ K2,
                      const u16* __restrict__ Vt, const float* __restrict__ sink,
                      const float* __restrict__ v_nulls, u16* __restrict__ ctxb)
{
    const int h  = blockIdx.x;
    const int qt = 15 - (int)blockIdx.y;
    const int s  = h % N_BR;
    const int tid  = threadIdx.x;
    const int lane = tid & 63, w = tid >> 6, g = lane >> 4, li = lane & 15;

    __shared__ __align__(16) u16 sK[8192];
    __shared__ __align__(16) u16 sV[8192];

    const u16* qrow = Q2 + ((size_t)h * T_SEQ + qt * 64 + w * 16 + li) * 64;
    bf16x8 qa[2];
    qa[0] = *reinterpret_cast<const bf16x8*>(qrow + g * 8);
    qa[1] = *reinterpret_cast<const bf16x8*>(qrow + 32 + g * 8);

    bf16x8 ones;
    #pragma unroll
    for (int e = 0; e < 8; ++e) ones[e] = (__bf16)1.0f;

    attn_stage_kv(0, 0, h, s, tid, K2, Vt, sK, sV);

    f32x4 acc[4];
    #pragma unroll
    for (int j = 0; j < 4; ++j)
        #pragma unroll
        for (int r = 0; r < 4; ++r) acc[j][r] = 0.f;
    f32x4 psacc;
    #pragma unroll
    for (int r = 0; r < 4; ++r) psacc[r] = 0.f;

    __syncthreads();

    const int qglob = qt * 64 + w * 16 + li;
    const int nt = qt + 1;
    int cur = 0;
    for (int kt = 0; kt < nt - 1; ++kt) {
        attn_stage_kv(cur ^ 1, (kt + 1) * 64, h, s, tid, K2, Vt, sK, sV);
        attn_tile_sw<false>(kt * 64, qglob, g, li,
                            sK + cur * 4096, sV + cur * 4096, qa, ones, acc, psacc);
        __syncthreads();
        cur ^= 1;
    }
    attn_tile_sw<true>(qt * 64, qglob, g, li,
                       sK + cur * 4096, sV + cur * 4096, qa, ones, acc, psacc);

    const float es = __expf(sink[h] - SM_OFF);
    const float rz = 1.0f / (psacc[0] + es);

    const int t = qt * 64 + w * 16 + li;
    u16* orow = ctxb + (size_t)t * NQ + h * 64;
    const float* vn = v_nulls + h * 64;
    #pragma unroll
    for (int j = 0; j < 4; ++j) {
        const int d0 = 16 * j + 4 * g;
        float4 vnv = *reinterpret_cast<const float4*>(&vn[d0]);
        ushort4 o;
        o.x = tobf((acc[j][0] + es * vnv.x) * rz);
        o.y = tobf((acc[j][1] + es * vnv.y) * rz);
        o.z = tobf((acc[j][2] + es * vnv.z) * rz);
        o.w = tobf((acc[j][3] + es * vnv.w) * rz);
        *reinterpret_cast<ushort4*>(&orow[d0]) = o;
    }
}

// ---------------------------------------------------------------------------
// launcher
// ---------------------------------------------------------------------------
extern "C" void kernel_launch(void* const* d_in, const int* in_sizes, int n_in,
                              void* d_out, int out_size, void* d_ws, size_t ws_size,
                              hipStream_t stream)
{
    (void)in_sizes; (void)n_in; (void)out_size; (void)ws_size;

    const float* x       = (const float*)d_in[0];
    const float* WV_w    = (const float*)d_in[1];
    const float* WV_b    = (const float*)d_in[2];
    const float* WK_w    = (const float*)d_in[3];
    const float* WK_b    = (const float*)d_in[4];
    const float* WQ_w    = (const float*)d_in[5];
    const float* Amat    = (const float*)d_in[6];
    const float* id_bias = (const float*)d_in[7];
    const float* sink    = (const float*)d_in[8];
    const float* v_nulls = (const float*)d_in[9];
    const float* WO_w    = (const float*)d_in[10];
    const float* WO_b    = (const float*)d_in[11];
    float* out = (float*)d_out;

    // ---- workspace carve ----
    float* tab    = (float*)d_ws;            // 65536 f
    float* mbias  = tab + 65536;             // 768 f
    float* kvbase = mbias + 768;             // 1572864 f : [1024][1536] K|V
    u16* Mth  = (u16*)(kvbase + 1572864);    // 589824
    u16* Mtl  = Mth + 589824;                // 589824
    u16* xh   = Mtl + 589824;                // 786432
    u16* wqt  = xh + 786432;                 // 7077888 (folded WQ^T bf16)
    u16* wkvt = wqt + 7077888;               // 1179648 ([WK^T|WV^T] bf16)
    u16* wot  = wkvt + 1179648;              // 7077888 (WO^T bf16)
    u16* K2   = wot + 7077888;               // 9437184
    u16* Vt   = K2 + 9437184;                // 786432
    u16* Q2   = Vt + 786432;                 // 9437184
    u16* ctxb = Q2 + 9437184;                // 9437184
    float* pkv = (float*)(ctxb + 9437184);   // 6291456 f (KV partials Z=4)

    // out-proj partials Z=8 (25.2 MB) overlay K2+Vt+Q2 (39.3 MB, dead post-attn)
    float* outpart = (float*)K2;

    const dim3 blk(256);

    // 1) mega prep: tables, M, mean-bias, x->bf16, W transposes
    prep_kernel<<<dim3(9107), blk, 0, stream>>>(
        x, xh, Amat, id_bias, Mth, Mtl, WO_b, mbias, tab, WO_w, wot, WK_w, WV_w, wkvt);

    // 2) fold M into WQ -> W'Q^T bf16
    fold_wq_kernel<<<dim3(H_TOT, 6), blk, 0, stream>>>(WQ_w, Mth, Mtl, wqt);

    // 3) fused K/V projection, split-K=4, XCD-swizzled + pipelined (384 blocks)
    gemm_bf16_kernel<<<dim3(384), blk, 0, stream>>>(
        xh, wkvt, pkv, T_SEQ, 1536, C_MODEL, 12, 8, 4);
    reduce_kv_kernel<<<dim3(1536), blk, 0, stream>>>(pkv, kvbase, WK_b, WV_b, 1572864, 4);

    // 4) merged wedge+rope K -> K2 and V transpose -> Vt
    wedge_vt_kernel<<<dim3(156, 16), blk, 0, stream>>>(
        kvbase, K2, Vt, Mth, Mtl, tab);

    // 5) Q projection with fused rope -> Q2 (64x128 tiles, pipelined, 1152 blocks)
    gemm_q_rope_kernel<<<dim3(1152), blk, 0, stream>>>(xh, wqt, tab, Q2);

    // 6) flash attention (swapped/permuted, exp2, dbuf) -> ctx bf16
    attn_mfma_kernel<<<dim3(H_TOT, 16), blk, 0, stream>>>(
        Q2, K2, Vt, sink, v_nulls, ctxb);

    // 7) output projection: 64x128 tiles, split-K=8, pipelined (768 blocks)
    gemm64_kernel<<<dim3(768), blk, 0, stream>>>(
        ctxb, wot, outpart, T_SEQ, C_MODEL, NQ, 6, 16, 8);
    reduce_kernel<<<dim3(768), blk, 0, stream>>>(
        outpart, out, mbias, 786432, C_MODEL, 8, 1.0f / 12.0f);
}